// Round 6
// baseline (137.388 us; speedup 1.0000x reference)
//
#include <hip/hip_runtime.h>
#include <hip/hip_bf16.h>
#include <stdint.h>

// Problem: B=4, C=256, O=256, H=W=64, K=3, K2=9, KK=2304
// ws: xT bf16 NHWC @0 (8388608) | yT @8388608 (8388608) | Wp2 @16777216
//     (1179648) | Bo (+147456)

typedef __bf16 bf16x8 __attribute__((ext_vector_type(8)));
typedef float  f32x4  __attribute__((ext_vector_type(4)));

__device__ __forceinline__ unsigned short f2bfu(float f) {
    union { float f; unsigned u; } v; v.f = f;
    return (unsigned short)((v.u + 0x8000u) >> 16);
}
__device__ __forceinline__ float lo16(unsigned u) {
    union { unsigned u; float f; } v; v.u = u << 16; return v.f;
}
__device__ __forceinline__ float hi16(unsigned u) {
    union { unsigned u; float f; } v; v.u = u & 0xFFFF0000u; return v.f;
}
__device__ __forceinline__ unsigned fbits(float f) {
    union { float f; unsigned u; } v; v.f = f; return v.u;
}
__device__ __forceinline__ unsigned blend2(unsigned u0, unsigned u1, unsigned u2, unsigned u3,
                                           float4 w) {
    float lo = w.x * lo16(u0) + w.y * lo16(u1) + w.z * lo16(u2) + w.w * lo16(u3);
    float hi = w.x * hi16(u0) + w.y * hi16(u1) + w.z * hi16(u2) + w.w * hi16(u3);
    unsigned rl = fbits(lo) + 0x8000u;
    unsigned rh = fbits(hi) + 0x8000u;
    return __builtin_amdgcn_perm(rh, rl, 0x07060302);
}

__device__ __forceinline__ void wait_ge(int* f, int v) {
    while (__hip_atomic_load(f, __ATOMIC_ACQUIRE, __HIP_MEMORY_SCOPE_WORKGROUP) < v)
        __builtin_amdgcn_s_sleep(1);
}
__device__ __forceinline__ void signal_one(int* f, int lane) {
    __threadfence_block();
    if (lane == 0)
        __hip_atomic_fetch_add(f, 1, __ATOMIC_RELEASE, __HIP_MEMORY_SCOPE_WORKGROUP);
}

// ---------------------------------------------------------------------------
// prep: fused {x,y transpose to NHWC bf16} + {packw} + {packow}.
// ---------------------------------------------------------------------------
__global__ __launch_bounds__(256) void prep_kernel(
    const float* __restrict__ x, const float* __restrict__ y,
    const float* __restrict__ ow, const float* __restrict__ dw,
    unsigned short* __restrict__ xT, unsigned short* __restrict__ yT,
    unsigned short* __restrict__ Wp2, unsigned short* __restrict__ Bo)
{
    __shared__ float tile[64 * 69];
    int blk = blockIdx.x;
    int t = threadIdx.x;
    if (blk < 2048) {
        const float* src = x; unsigned short* dst = xT;
        if (blk >= 1024) { src = y; dst = yT; blk -= 1024; }
        int cq = blk & 3;
        int bh = blk >> 2;
        int w4 = t & 15, cl0 = t >> 4;
        const float* s = src + ((size_t)(bh >> 6) * 256 + cq * 64) * 4096 + (size_t)(bh & 63) * 64;
#pragma unroll
        for (int p = 0; p < 4; ++p) {
            int cl = p * 16 + cl0;
            float4 v = *(const float4*)&s[(size_t)cl * 4096 + w4 * 4];
            tile[(w4 * 4 + 0) * 69 + cl] = v.x;
            tile[(w4 * 4 + 1) * 69 + cl] = v.y;
            tile[(w4 * 4 + 2) * 69 + cl] = v.z;
            tile[(w4 * 4 + 3) * 69 + cl] = v.w;
        }
        __syncthreads();
        unsigned short* d = dst + (size_t)bh * 16384 + cq * 64;
#pragma unroll
        for (int p = 0; p < 4; ++p) {
            int w = p * 16 + cl0;
            float4 v = *(const float4*)&tile[w * 69 + w4 * 4];
            ushort4 r = make_ushort4(f2bfu(v.x), f2bfu(v.y), f2bfu(v.z), f2bfu(v.w));
            *(ushort4*)&d[w * 256 + w4 * 4] = r;
        }
    } else if (blk < 2336) {
        int tid = (blk - 2048) * 256 + t;
        int q8 = tid >> 8;
        int o  = tid & 255;
        int k0 = q8 * 8;
        int tap = k0 >> 8, c0 = k0 & 255;
        const float* s = dw + o * 2304 + c0 * 9 + tap;
        ushort4 r0 = make_ushort4(f2bfu(s[0]), f2bfu(s[9]), f2bfu(s[18]), f2bfu(s[27]));
        ushort4 r1 = make_ushort4(f2bfu(s[36]), f2bfu(s[45]), f2bfu(s[54]), f2bfu(s[63]));
        *(ushort4*)&Wp2[tid * 8 + 0] = r0;
        *(ushort4*)&Wp2[tid * 8 + 4] = r1;
    } else {
        int idx = (blk - 2336) * 256 + t;
        int j = idx & 7;
        int n = (idx >> 3) & 31;
        int lq = (idx >> 8) & 3;
        int kg = idx >> 10;
        int k = kg * 32 + lq * 8 + j;
        int tap = k >> 8, c = k & 255;
        float v = (n < 18) ? ow[n * 2304 + c * 9 + tap] : 0.f;
        Bo[idx] = f2bfu(v);
    }
}

// ---------------------------------------------------------------------------
// Fused deform, producer-consumer.  Grid 256 = (b,h), 1024 thr = 16 waves.
// Prologue (all waves): offsets conv via MFMA -> red LDS -> bilinear params.
// Main: waves 0-7 = producers: gather+blend tap into 3-slot LDS ring, signal
//       ready[tap]; wait done[tap-3] before reusing a slot.
//       waves 8-15 = consumers: each owns N-slice [ns*32,+32), FULL K; waits
//       ready[tap], MFMAs 8 K-chunks (A from LDS slot, B from L2 Wp2),
//       signals done[tap].  No __syncthreads in the tap loop; VMEM, blend
//       VALU, LDS, MFMA pipes overlap across wave groups.
// Epilogue: consumers hold full-K acc -> direct bias+store (no K-reduce).
// LDS: slots 3x32768 @0 | pw 9216 @98304 | pi 9216 @107520 | flags @116736
//      (prologue red 67584 @0 overlaps slots; dead before main loop)
// ---------------------------------------------------------------------------
__global__ __launch_bounds__(1024) void deform_kernel(
    const unsigned short* __restrict__ xT,
    const unsigned short* __restrict__ yT,
    const unsigned short* __restrict__ Wp2,
    const unsigned short* __restrict__ Bo,
    const float* __restrict__ ob,
    const float* __restrict__ db,
    float* __restrict__ out)
{
    __shared__ __align__(16) unsigned char smem[116864];
    float*  red    = (float*)smem;
    float4* pw_lds = (float4*)(smem + 98304);
    int4*   pi_lds = (int4*)(smem + 98304 + 9216);
    int*    ready  = (int*)(smem + 116736);      // [9]
    int*    done   = (int*)(smem + 116736 + 36); // [9]

    int blk = blockIdx.x;
    int lb = (blk & 7) * 32 + (blk >> 3);        // XCD-slab swizzle
    int b = lb >> 6, h = lb & 63;
    int t = threadIdx.x;
    int wv = t >> 6, lane = t & 63;
    int ln = lane & 15, lq = lane >> 4;

    const unsigned short* xtb = xT + (size_t)b * (64 * 64 * 256);

    if (t < 18) ((int*)(smem + 116736))[t] = 0;

    // ================= offsets prologue (all 16 waves) =================
    {
        int kq = wv >> 1, mh = wv & 1;
        f32x4 oacc[2][2];
#pragma unroll
        for (int m16 = 0; m16 < 2; ++m16)
#pragma unroll
            for (int nt = 0; nt < 2; ++nt)
                oacc[m16][nt] = (f32x4){0.f, 0.f, 0.f, 0.f};
        for (int u = kq * 9; u < kq * 9 + 9; ++u) {
            int tap = u >> 3, kc = u & 7;
            int ki = tap / 3, kj = tap - ki * 3;
            int hr = h + ki - 1;
            bf16x8 b0 = *(const bf16x8*)&Bo[(tap * 8 + kc) * 1024 + lq * 256 + ln * 8];
            bf16x8 b1 = *(const bf16x8*)&Bo[(tap * 8 + kc) * 1024 + lq * 256 + (16 + ln) * 8];
#pragma unroll
            for (int m16 = 0; m16 < 2; ++m16) {
                int wr = mh * 32 + m16 * 16 + ln + kj - 1;
                bf16x8 af = (bf16x8)(__bf16)0.0f;
                if (hr >= 0 && hr < 64 && wr >= 0 && wr < 64)
                    af = *(const bf16x8*)&yT[((size_t)(b * 64 + hr) * 64 + wr) * 256 + kc * 32 + lq * 8];
                oacc[m16][0] = __builtin_amdgcn_mfma_f32_16x16x32_bf16(af, b0, oacc[m16][0], 0, 0, 0);
                oacc[m16][1] = __builtin_amdgcn_mfma_f32_16x16x32_bf16(af, b1, oacc[m16][1], 0, 0, 0);
            }
        }
        float* rz = red + (size_t)(kq * 2 + mh) * 1056;
#pragma unroll
        for (int m16 = 0; m16 < 2; ++m16)
#pragma unroll
            for (int nt = 0; nt < 2; ++nt) {
                int o_l = nt * 16 + ln;
#pragma unroll
                for (int r = 0; r < 4; ++r)
                    rz[o_l * 33 + m16 * 16 + lq * 4 + r] = oacc[m16][nt][r];
            }
    }
    __syncthreads();
    if (t < 576) {
        int tap = t >> 6, pos = t & 63;
        int mh_p = pos >> 5, pl = pos & 31;
        float dy = ob[2 * tap], dx = ob[2 * tap + 1];
#pragma unroll
        for (int kq = 0; kq < 8; ++kq) {
            const float* rz = red + (size_t)(kq * 2 + mh_p) * 1056;
            dy += rz[(2 * tap) * 33 + pl];
            dx += rz[(2 * tap + 1) * 33 + pl];
        }
        int ki = tap / 3, kj = tap - ki * 3;
        float py = (float)(h - 1 + ki) + dy;
        float px = (float)(pos - 1 + kj) + dx;
        float y0 = floorf(py), x0 = floorf(px);
        float wy1 = py - y0, wx1 = px - x0;
        float wy0 = 1.f - wy1, wx0 = 1.f - wx1;
        float y1 = y0 + 1.f, x1 = x0 + 1.f;
        float vy0 = (y0 >= 0.f && y0 <= 63.f) ? 1.f : 0.f;
        float vy1 = (y1 >= 0.f && y1 <= 63.f) ? 1.f : 0.f;
        float vx0 = (x0 >= 0.f && x0 <= 63.f) ? 1.f : 0.f;
        float vx1 = (x1 >= 0.f && x1 <= 63.f) ? 1.f : 0.f;
        int iy0 = (int)fminf(fmaxf(y0, 0.f), 63.f);
        int iy1 = (int)fminf(fmaxf(y1, 0.f), 63.f);
        int ix0 = (int)fminf(fmaxf(x0, 0.f), 63.f);
        int ix1 = (int)fminf(fmaxf(x1, 0.f), 63.f);
        pw_lds[t] = make_float4(wy0 * wx0 * vy0 * vx0, wy0 * wx1 * vy0 * vx1,
                                wy1 * wx0 * vy1 * vx0, wy1 * wx1 * vy1 * vx1);
        pi_lds[t] = make_int4((iy0 * 64 + ix0) * 256, (iy0 * 64 + ix1) * 256,
                              (iy1 * 64 + ix0) * 256, (iy1 * 64 + ix1) * 256);
    }
    __syncthreads();   // red dead; slots live; flags zeroed

    if (wv < 8) {
        // ===================== PRODUCER =====================
        int gr = lane & 31, half = lane >> 5, c0 = gr * 8;
#pragma unroll 1
        for (int tap = 0; tap < 9; ++tap) {
            if (tap >= 3) wait_ge(&done[tap - 3], 8);
            float4 gw[4]; uint4 ga[4][4];
#pragma unroll
            for (int it = 0; it < 4; ++it) {
                int pos = wv * 2 + half + it * 16;
                gw[it] = pw_lds[tap * 64 + pos];
                int4 p = pi_lds[tap * 64 + pos];
                ga[it][0] = *(const uint4*)&xtb[p.x + c0];
                ga[it][1] = *(const uint4*)&xtb[p.y + c0];
                ga[it][2] = *(const uint4*)&xtb[p.z + c0];
                ga[it][3] = *(const uint4*)&xtb[p.w + c0];
            }
            unsigned short* buf = (unsigned short*)(smem + (tap % 3) * 32768);
#pragma unroll
            for (int it = 0; it < 4; ++it) {
                int pos = wv * 2 + half + it * 16;
                uint4 res;
                res.x = blend2(ga[it][0].x, ga[it][1].x, ga[it][2].x, ga[it][3].x, gw[it]);
                res.y = blend2(ga[it][0].y, ga[it][1].y, ga[it][2].y, ga[it][3].y, gw[it]);
                res.z = blend2(ga[it][0].z, ga[it][1].z, ga[it][2].z, ga[it][3].z, gw[it]);
                res.w = blend2(ga[it][0].w, ga[it][1].w, ga[it][2].w, ga[it][3].w, gw[it]);
                *(uint4*)&buf[pos * 256 + (gr ^ (pos & 7)) * 8] = res;
            }
            signal_one(&ready[tap], lane);
        }
    } else {
        // ===================== CONSUMER =====================
        int ns = wv - 8;
        f32x4 acc[4][2];
#pragma unroll
        for (int ms = 0; ms < 4; ++ms)
#pragma unroll
            for (int nt = 0; nt < 2; ++nt)
                acc[ms][nt] = (f32x4){0.f, 0.f, 0.f, 0.f};
#pragma unroll 1
        for (int tap = 0; tap < 9; ++tap) {
            wait_ge(&ready[tap], 8);
            const unsigned short* Ab = (const unsigned short*)(smem + (tap % 3) * 32768);
#pragma unroll 2
            for (int kc = 0; kc < 8; ++kc) {
                int g = kc * 4 + lq;
                bf16x8 af[4];
#pragma unroll
                for (int ms = 0; ms < 4; ++ms) {
                    int row = ms * 16 + ln;
                    af[ms] = *(const bf16x8*)&Ab[row * 256 + (g ^ (row & 7)) * 8];
                }
                int kg = tap * 8 + kc;
                bf16x8 bfr[2];
#pragma unroll
                for (int nt = 0; nt < 2; ++nt)
                    bfr[nt] = *(const bf16x8*)&Wp2[((kg * 4 + lq) * 256 + ns * 32 + nt * 16 + ln) * 8];
#pragma unroll
                for (int ms = 0; ms < 4; ++ms)
#pragma unroll
                    for (int nt = 0; nt < 2; ++nt)
                        acc[ms][nt] = __builtin_amdgcn_mfma_f32_16x16x32_bf16(af[ms], bfr[nt], acc[ms][nt], 0, 0, 0);
            }
            signal_one(&done[tap], lane);
        }
        // epilogue: full-K acc -> bias + store (D: col=ln -> o_l, row=lq*4+r -> w)
#pragma unroll
        for (int nt = 0; nt < 2; ++nt) {
            int o = ns * 32 + nt * 16 + ln;
            float bias = db[o];
            float* ob_ptr = out + ((size_t)(b * 256 + o)) * 4096 + h * 64;
#pragma unroll
            for (int ms = 0; ms < 4; ++ms) {
                f32x4 a = acc[ms][nt];
                float4 st = make_float4(a[0] + bias, a[1] + bias, a[2] + bias, a[3] + bias);
                *(float4*)&ob_ptr[ms * 16 + lq * 4] = st;
            }
        }
    }
}

extern "C" void kernel_launch(void* const* d_in, const int* in_sizes, int n_in,
                              void* d_out, int out_size, void* d_ws, size_t ws_size,
                              hipStream_t stream) {
    const float* x  = (const float*)d_in[0];
    const float* y  = (const float*)d_in[1];
    const float* ow = (const float*)d_in[2];
    const float* ob = (const float*)d_in[3];
    const float* dw = (const float*)d_in[4];
    const float* db = (const float*)d_in[5];
    float* out = (float*)d_out;

    char* ws = (char*)d_ws;
    unsigned short* xT  = (unsigned short*)(ws);
    unsigned short* yT  = (unsigned short*)(ws + 8388608);
    unsigned short* Wp2 = (unsigned short*)(ws + 16777216);
    unsigned short* Bo  = (unsigned short*)(ws + 16777216 + 1179648);

    hipLaunchKernelGGL(prep_kernel, dim3(2624), dim3(256), 0, stream,
                       x, y, ow, dw, xT, yT, Wp2, Bo);
    hipLaunchKernelGGL(deform_kernel, dim3(256), dim3(1024), 0, stream,
                       xT, yT, Wp2, Bo, ob, db, out);
}